// Round 7
// baseline (279.974 us; speedup 1.0000x reference)
//
#include <hip/hip_runtime.h>
#include <hip/hip_bf16.h>

typedef __bf16 bf16_t;
typedef __bf16 bf16x8 __attribute__((ext_vector_type(8)));
typedef float f32x16 __attribute__((ext_vector_type(16)));

// ---------------------------------------------------------------------------
// fused fp32 -> bf16 cast for 3 arrays (one launch; memory-bound)
// ---------------------------------------------------------------------------
__global__ __launch_bounds__(256) void cast3_f32_to_bf16(
    const float* __restrict__ a, bf16_t* __restrict__ ao, int na8,
    const float* __restrict__ b, bf16_t* __restrict__ bo, int nb8,
    const float* __restrict__ c, bf16_t* __restrict__ co, int nc8) {
  int i = blockIdx.x * blockDim.x + threadIdx.x;
  const float* in;
  bf16_t* out;
  int j;
  if (i < na8) {
    in = a; out = ao; j = i;
  } else if (i < na8 + nb8) {
    in = b; out = bo; j = i - na8;
  } else if (i < na8 + nb8 + nc8) {
    in = c; out = co; j = i - na8 - nb8;
  } else {
    return;
  }
  const float4* in4 = (const float4*)in;
  float4 f0 = in4[2 * j];
  float4 f1 = in4[2 * j + 1];
  bf16x8 o;
  o[0] = (bf16_t)f0.x; o[1] = (bf16_t)f0.y;
  o[2] = (bf16_t)f0.z; o[3] = (bf16_t)f0.w;
  o[4] = (bf16_t)f1.x; o[5] = (bf16_t)f1.y;
  o[6] = (bf16_t)f1.z; o[7] = (bf16_t)f1.w;
  ((bf16x8*)out)[j] = o;
}

// ---------------------------------------------------------------------------
// C[M,N] = A[M,K] * B[N,K]^T + bias[N], optional fused swish-poly.
//
// ONE-BARRIER SOFTWARE PIPELINE (R6 post-mortem: both GEMMs cost ~1800 cyc
// per block-iter with only 512 CU-cyc of MFMA — per-iteration latency, not
// bandwidth, is the binding constraint).
//   body(j): [1] global_load tile j+2 -> reg set S[j&1] (issued early)
//            [2] compute tile j from LDS buf[j&1]
//            [3] ds_write tile j+1 from S[(j+1)&1] (loaded early in body j-1
//                -> prefetch distance ~1.7 iters ~2000 cyc >> HBM 900)
//            [4] __syncthreads()  (the ONLY barrier)
// Plain global_load->VGPR has no LDS visibility requirement at s_barrier, so
// the barrier does not drain the loads in flight (unlike global_load_lds).
// Ping-pong unrolled x2 so register-set indices are static (no scratch).
//
// Block 256x128, BK=64, 4 waves (2x2), wave tile 128x64 via
// mfma_f32_32x32x16_bf16 (4 A x 2 B frags x 4 ksteps = 32 MFMA/iter/wave).
// LDS: dbuf A 2x32KB + B 2x16KB = 96 KB -> 1 block/CU, 4 waves.
//
// LDS rows = 64 elems = 128 B = 8 granules of 16 B; bank group == granule.
// Swizzle phys = logical ^ (row&7) (R5/R6-proven):
//   write: lane l -> row base+(l>>3), phys granule l&7, data from global
//          chunk (l&7)^(l>>3).
//   read:  lane l row l&31, logical (s<<1)|(l>>5) -> phys ^ (l&7).
// (SQ_LDS_BANK_CONFLICT will still read ~4 cyc per ds_read_b128 — measured
//  constant across R4/R5/R6, inherent to wave64 b128, not a real conflict.)
//
// SWISH=true -> Cout bf16 (swish(h)); SWISH=false -> Cout fp32 (h).
// Requires: M%256==0, N%128==0, K%64==0, (K/64)%2==0, K/64>=2.
// ---------------------------------------------------------------------------
#define STAGE_LOAD(SET, KT)                                          \
  {                                                                  \
    const int kt_ = (KT);                                            \
    _Pragma("unroll") for (int r = 0; r < 8; ++r)                    \
        SET[r] = *(const bf16x8*)(gA + kt_ + (size_t)(r * 8) * K);   \
    _Pragma("unroll") for (int r = 0; r < 4; ++r)                    \
        SET[8 + r] = *(const bf16x8*)(gB + kt_ + (size_t)(r * 8) * K); \
  }

#define STAGE_WRITE(SET, BUFSEL)                                        \
  {                                                                     \
    _Pragma("unroll") for (int r = 0; r < 8; ++r)                       \
        *(bf16x8*)(sA + (BUFSEL) * (256 * 64) + wAoff + r * 512) = SET[r]; \
    _Pragma("unroll") for (int r = 0; r < 4; ++r)                       \
        *(bf16x8*)(sB + (BUFSEL) * (128 * 64) + wBoff + r * 512) =      \
            SET[8 + r];                                                 \
  }

#define COMPUTE(BUFSEL)                                                 \
  {                                                                     \
    const bf16_t* bA = sA + (BUFSEL) * (256 * 64);                      \
    const bf16_t* bB = sB + (BUFSEL) * (128 * 64);                      \
    _Pragma("unroll") for (int s = 0; s < 4; ++s) {                     \
      const int sx = s << 4;                                            \
      bf16x8 af[4], bg[2];                                              \
      _Pragma("unroll") for (int i = 0; i < 4; ++i)                     \
          af[i] = *(const bf16x8*)(bA + (offA[i] ^ sx));                \
      _Pragma("unroll") for (int j = 0; j < 2; ++j)                     \
          bg[j] = *(const bf16x8*)(bB + (offB[j] ^ sx));                \
      _Pragma("unroll") for (int i = 0; i < 4; ++i)                     \
          _Pragma("unroll") for (int j = 0; j < 2; ++j)                 \
              acc[i][j] = __builtin_amdgcn_mfma_f32_32x32x16_bf16(      \
                  af[i], bg[j], acc[i][j], 0, 0, 0);                    \
    }                                                                   \
  }

template <bool SWISH>
__global__ __launch_bounds__(256, 1) void gemm_bt(
    const bf16_t* __restrict__ A, const bf16_t* __restrict__ B,
    const float* __restrict__ bias, void* __restrict__ Cout,
    int M, int N, int K, int XW, int px, int py) {
  const int tid = threadIdx.x;
  const int wave = tid >> 6;
  const int lane = tid & 63;

  // ---- XCD-aware block swizzle (bid%8 = XCD round-robin assumption) ----
  const int bid = blockIdx.x;
  const int xcd = bid & 7;
  const int idx = bid >> 3;
  const int cx = xcd % XW;
  const int cy = xcd / XW;
  const int bx = cx * px + idx % px;
  const int by = cy * py + idx / px;
  const int tileM = by << 8;  // 256 rows
  const int tileN = bx << 7;  // 128 cols

  __shared__ __align__(16) bf16_t sA[2 * 256 * 64];  // 64 KB
  __shared__ __align__(16) bf16_t sB[2 * 128 * 64];  // 32 KB

  // ---- staging geometry ----
  // wave w: A rows [w*64, w*64+64) in 8 loads; B rows [w*32, w*32+32) in 4.
  const int lrow = lane >> 3;                  // 0..7
  const int gch = ((lane & 7) ^ lrow) << 3;    // swizzled global chunk
  const bf16_t* gA = A + (size_t)(tileM + (wave << 6) + lrow) * K + gch;
  const bf16_t* gB = B + (size_t)(tileN + (wave << 5) + lrow) * K + gch;
  // LDS write offsets (elements, buffer 0); +r*512 per load row-group
  const int wAoff = ((wave << 6) + lrow) * 64 + ((lane & 7) << 3);
  const int wBoff = ((wave << 5) + lrow) * 64 + ((lane & 7) << 3);

  // ---- fragment read offsets (elements), kstep 0 ----
  const int wr = wave >> 1, wc = wave & 1;
  const int frow = lane & 31;
  const int p0 = (((lane >> 5) ^ (lane & 7)) << 3);
  int offA[4], offB[2];
#pragma unroll
  for (int i = 0; i < 4; ++i)
    offA[i] = (wr * 128 + i * 32 + frow) * 64 + p0;
#pragma unroll
  for (int j = 0; j < 2; ++j)
    offB[j] = (wc * 64 + j * 32 + frow) * 64 + p0;

  f32x16 acc[4][2] = {};

  const int niter = K >> 6;

  // ---- prologue: tile0 -> S0 -> buf0; tile1 -> S1 ----
  bf16x8 S0[12], S1[12];
  STAGE_LOAD(S0, 0);
  STAGE_WRITE(S0, 0);
  STAGE_LOAD(S1, 64);
  __syncthreads();

  for (int j = 0; j < niter; j += 2) {
    // ---- even body: compute buf0 (tile j) ----
    if (j + 2 < niter) STAGE_LOAD(S0, (j + 2) << 6);
    COMPUTE(0);
    STAGE_WRITE(S1, 1);  // tile j+1 (j+1 < niter always: niter even)
    __syncthreads();
    // ---- odd body: compute buf1 (tile j+1) ----
    if (j + 3 < niter) STAGE_LOAD(S1, (j + 3) << 6);
    COMPUTE(1);
    if (j + 2 < niter) STAGE_WRITE(S0, 0);  // tile j+2
    __syncthreads();
  }

  // ---- epilogue: 32x32 C/D: col = lane&31, row = (r&3)+8*(r>>2)+4*(lane>>5)
  const int halfsel = (lane >> 5) << 2;
#pragma unroll
  for (int i = 0; i < 4; ++i) {
    const int row0 = tileM + wr * 128 + i * 32 + halfsel;
#pragma unroll
    for (int j = 0; j < 2; ++j) {
      const int col = tileN + wc * 64 + j * 32 + (lane & 31);
      const float bv = bias[col];
#pragma unroll
      for (int r = 0; r < 16; ++r) {
        const int row = row0 + (r & 3) + ((r >> 2) << 3);
        float h = acc[i][j][r] + bv;
        if constexpr (SWISH) {
          float h3 = h * h * h;
          float sw = h * (0.5f + 0.25f * h - 0.0208f * h3);
          ((bf16_t*)Cout)[(size_t)row * N + col] = (bf16_t)sw;
        } else {
          ((float*)Cout)[(size_t)row * N + col] = h;
        }
      }
    }
  }
}

// ---------------------------------------------------------------------------
// launch
// ---------------------------------------------------------------------------
extern "C" void kernel_launch(void* const* d_in, const int* in_sizes, int n_in,
                              void* d_out, int out_size, void* d_ws,
                              size_t ws_size, hipStream_t stream) {
  const float* X  = (const float*)d_in[0];  // [B,S,D] = [M,D]
  const float* W1 = (const float*)d_in[1];  // [F,D]
  const float* b1 = (const float*)d_in[2];  // [F]
  const float* W2 = (const float*)d_in[3];  // [D,F]
  const float* b2 = (const float*)d_in[4];  // [D]
  float* out = (float*)d_out;               // [M,D]

  const int F = in_sizes[2];      // 4096
  const int D = in_sizes[4];      // 1024
  const int M = in_sizes[0] / D;  // 8192

  // workspace layout (bf16): Xb[M*D] | W1b[F*D] | W2b[D*F] | SW[M*F]
  bf16_t* Xb  = (bf16_t*)d_ws;
  bf16_t* W1b = Xb + (size_t)M * D;
  bf16_t* W2b = W1b + (size_t)F * D;
  bf16_t* SW  = W2b + (size_t)D * F;

  const int nX = (M * D) / 8, nW1 = (F * D) / 8, nW2 = (D * F) / 8;
  const int nTot = nX + nW1 + nW2;
  cast3_f32_to_bf16<<<(nTot + 255) / 256, 256, 0, stream>>>(
      X, Xb, nX, W1, W1b, nW1, W2, W2b, nW2);

  // GEMM1: SW[M,F] = swish(Xb @ W1b^T + b1)  (bf16 out)
  // grid: gy = 8192/256 = 32, gx = 4096/128 = 32 -> 1024 blocks (4 rounds
  // at 1 block/CU). XCDs 2x4: per-XCD footprint A 4 MB + B 4 MB.
  {
    const int gx = F / 128, gy = M / 256;
    const int XW = 2, XH = 4;
    const int px = gx / XW, py = gy / XH;
    gemm_bt<true><<<gx * gy, 256, 0, stream>>>(
        Xb, W1b, b1, (void*)SW, M, F, D, XW, px, py);
  }

  // GEMM2: out[M,D] = SW @ W2b^T + b2        (fp32 out)
  // grid: gy = 32, gx = 1024/128 = 8 -> 256 blocks (1/CU, one round).
  // XCDs 1x8 (y-partition): per-XCD SW strip (8 MB) streamed once; W2 8 MB
  // thrashes L2 but stays L3-resident (latency covered by the pipeline).
  {
    const int gx = D / 128, gy = M / 256;
    const int XW = 1, XH = 8;
    const int px = gx / XW, py = gy / XH;
    gemm_bt<false><<<gx * gy, 256, 0, stream>>>(
        SW, W2b, b2, (void*)out, M, D, F, XW, px, py);
  }
}

#undef STAGE_LOAD
#undef STAGE_WRITE
#undef COMPUTE